// Round 14
// baseline (46.866 us; speedup 1.0000x reference)
//
#include <hip/hip_runtime.h>
#include <hip/hip_bf16.h>
#include <math.h>

#define NFREQ 1024      // N_FFT//2
#define NMELS 256
#define NNOTES 82
#define KPAD  96        // K padded to multiple of 32 for mfma 16x16x32
#define KMAXH 400

#define TROWS 32        // rows per tile
#define TFLOAT (TROWS * NNOTES)      // 2624 floats per tile
#define BUFSTRIDE (TFLOAT + 16)      // +16 zero pad (fragment overrun, k>=82)

typedef __attribute__((ext_vector_type(8))) short bf16x8;
typedef __attribute__((ext_vector_type(4))) float f32x4;

__device__ inline unsigned short f2bf(float x) {
    union { float f; unsigned int u; } c; c.f = x;
    unsigned int r = c.u + 0x7FFFu + ((c.u >> 16) & 1u);   // round-to-nearest-even
    return (unsigned short)(r >> 16);
}

// ------------- Kernel AB (merged): harmonic cols (LDS) -> mel -> log -> bf16 ----
__global__ __launch_bounds__(256) void harm_prep(
    const float* __restrict__ omega,
    const float* __restrict__ stdv,
    const float* __restrict__ mask,
    unsigned short* __restrict__ wT)
{
    int n   = blockIdx.x;            // 0..95 (82..95 = K-pad rows)
    int tid = threadIdx.x;
    if (n >= NNOTES) {               // zero pad rows: (k>=82) x (any y bits) = 0
        wT[tid * KPAD + n] = 0;
        return;
    }
    __shared__ float cols[NFREQ];

    // phase 1: cols[fi] = sum_k omega*mask*gauss for this note
    float f0 = 27.5f * exp2f((float)n / 12.0f);
    for (int fi = tid; fi < NFREQ; fi += 256) {
        float f = 11025.0f * (float)fi / 1023.0f;
        const float RAD = 80.0f;                           // 16*sigma at sigma=5
        int klo = (int)ceilf((f - RAD) / f0);
        int khi = (int)floorf((f + RAD) / f0);
        if (klo < 1) klo = 1;
        if (khi > KMAXH) khi = KMAXH;
        float acc = 0.0f;
        for (int k = klo; k <= khi; ++k) {
            int idx = n * KMAXH + (k - 1);
            float mk = mask[idx];
            if (mk == 0.0f) continue;
            float c = f0 * (float)k;
            float s = stdv[idx];
            float d = (f - c) / s;
            float e = 0.5f * d * d;
            if (e > 90.0f) continue;
            acc += omega[idx] * mk * expf(-e);
        }
        cols[fi] = acc;
    }
    __syncthreads();

    // phase 2 (f32): mel triangle m = tid over LDS cols, log-compress, bf16
    int m = tid;
    const float logstep = 0.06875177742094911f;            // log(6.4)/27
    const float mel_max = 15.0f + logf(11.025f) / logstep; // hz_to_mel(11025)
    float mm0 = mel_max * (float)m       / 257.0f;
    float mm1 = mel_max * (float)(m + 1) / 257.0f;
    float mm2 = mel_max * (float)(m + 2) / 257.0f;
    float mf0 = (mm0 >= 15.0f) ? 1000.0f * expf(logstep * (mm0 - 15.0f)) : mm0 * (200.0f / 3.0f);
    float mf1 = (mm1 >= 15.0f) ? 1000.0f * expf(logstep * (mm1 - 15.0f)) : mm1 * (200.0f / 3.0f);
    float mf2 = (mm2 >= 15.0f) ? 1000.0f * expf(logstep * (mm2 - 15.0f)) : mm2 * (200.0f / 3.0f);
    float inv_lo = 1.0f / (mf1 - mf0);
    float inv_hi = 1.0f / (mf2 - mf1);
    float enorm  = 2.0f / (mf2 - mf0);
    int lo = (int)floorf(mf0 * (1024.0f / 11025.0f)) - 1;
    int hi = (int)ceilf (mf2 * (1024.0f / 11025.0f)) + 1;
    if (lo < 0) lo = 0;
    if (hi > 1023) hi = 1023;
    float acc = 0.0f;
    for (int fi = lo; fi <= hi; ++fi) {
        float ff = 11025.0f * (float)(fi + 1) / 1024.0f;
        float wt = fminf((ff - mf0) * inv_lo, (mf2 - ff) * inv_hi);
        wt = fmaxf(0.0f, wt) * enorm;
        acc += wt * cols[fi];
    }
    const float X_MIN = -13.815510557964274f;              // log(1e-6)
    const float X_MAX = 3.0f;
    float x = logf(acc + 1e-6f);
    x = fminf(fmaxf(x, X_MIN), X_MAX);
    wT[m * KPAD + n] = f2bf((x - X_MIN) * (1.0f / (X_MAX - X_MIN)));
}

// ---------------- Kernel C: rolling 4-tile, triple-buffer, counted vmcnt --------
// Block = 4 waves, 4 tiles x (32 rows x 256 cols); grid 1024 = EXACTLY 4
// blocks/CU, uniform -> zero tail/skew. Triple-buffered 31.7 KB LDS; per iter:
// {vmcnt(N) for tile-t DMA only; s_barrier; issue DMA(t+2); compute t}. Every
// barrier is crossed with the next tiles' DMAs + prev stores in flight. vmcnt
// literals from exact queue accounting (3 DMA/tile/wave, 8 st/tile/wave):
// iter0=3, iter1=11, iter2=19, iter3=16. bw fragments loaded once, reused 4x.
// Each buffer has a 16-float zero pad: row-31 fragments read k in [82,96) =
// 14 floats past the tile -> pad, never DMA-overwritten, x zero wT pad rows.
__device__ __forceinline__ void gload16(const void* g, void* l) {
    __builtin_amdgcn_global_load_lds(
        (const __attribute__((address_space(1))) unsigned int*)g,
        (__attribute__((address_space(3))) unsigned int*)l, 16, 0, 0);
}

__device__ __forceinline__ void dma_tile(const float* ytile, float* buf, int wid, int lane) {
    // 2624 floats = 656 16B units; wave w stages units [w*164, (w+1)*164)
    int base = wid * 164;
    gload16(ytile + 4 * (base + lane),       buf + 4 * base);
    gload16(ytile + 4 * (base + 64 + lane),  buf + 4 * (base + 64));
    if (lane < 36)
        gload16(ytile + 4 * (base + 128 + lane), buf + 4 * (base + 128));
}

__device__ __forceinline__ void compute_tile32(
    const float* __restrict__ bufp, const bf16x8 bw[3][4],
    float* __restrict__ out, size_t rowbase, int r16, int g4, int c0)
{
    #pragma unroll
    for (int i = 0; i < 2; ++i) {
        const float* yrow = bufp + (i * 16 + r16) * NNOTES;
        bf16x8 ay[3];
        #pragma unroll
        for (int kb = 0; kb < 3; ++kb) {
            const float* fr = yrow + kb * 32 + g4 * 8;
            float2 a0 = *(const float2*)(fr + 0);
            float2 a1 = *(const float2*)(fr + 2);
            float2 a2 = *(const float2*)(fr + 4);
            float2 a3 = *(const float2*)(fr + 6);
            union { unsigned u[4]; bf16x8 v; } A;
            asm("v_cvt_pk_bf16_f32 %0, %1, %2" : "=v"(A.u[0]) : "v"(a0.x), "v"(a0.y));
            asm("v_cvt_pk_bf16_f32 %0, %1, %2" : "=v"(A.u[1]) : "v"(a1.x), "v"(a1.y));
            asm("v_cvt_pk_bf16_f32 %0, %1, %2" : "=v"(A.u[2]) : "v"(a2.x), "v"(a2.y));
            asm("v_cvt_pk_bf16_f32 %0, %1, %2" : "=v"(A.u[3]) : "v"(a3.x), "v"(a3.y));
            ay[kb] = A.v;
        }
        f32x4 acc[4];
        #pragma unroll
        for (int c = 0; c < 4; ++c) acc[c] = (f32x4){0.f, 0.f, 0.f, 0.f};
        #pragma unroll
        for (int kb = 0; kb < 3; ++kb)
            #pragma unroll
            for (int c = 0; c < 4; ++c)
                acc[c] = __builtin_amdgcn_mfma_f32_16x16x32_bf16(bw[kb][c], ay[kb], acc[c], 0, 0, 0);
        float* orow = out + (rowbase + i * 16 + r16) * NMELS + c0 + g4 * 4;
        #pragma unroll
        for (int c = 0; c < 4; ++c)
            *(f32x4*)(orow + c * 16) = acc[c];
    }
}

#define SBAR() do { __builtin_amdgcn_sched_barrier(0); \
                    __builtin_amdgcn_s_barrier(); \
                    __builtin_amdgcn_sched_barrier(0); } while (0)

__global__ __launch_bounds__(256, 4) void harm_gemm(
    const float* __restrict__ y,
    const unsigned short* __restrict__ wT,
    float* __restrict__ out)
{
    __shared__ float yf[3 * BUFSTRIDE];
    int tid  = threadIdx.x;
    int lane = tid & 63;
    int wid  = tid >> 6;
    int r16  = lane & 15;
    int g4   = lane >> 4;
    int c0   = wid * 64;
    size_t t0 = (size_t)blockIdx.x * 4;        // first tile index (32-row tiles)

    // zero the 3 per-buffer pads (never DMA-overwritten)
    if (tid < 48) yf[(tid >> 4) * BUFSTRIDE + TFLOAT + (tid & 15)] = 0.f;

    // ---- bw fragments (12 loads), then prologue DMAs t0, t0+1 ----
    bf16x8 bw[3][4];
    #pragma unroll
    for (int kb = 0; kb < 3; ++kb)
        #pragma unroll
        for (int c = 0; c < 4; ++c)
            bw[kb][c] = *(const bf16x8*)(wT + (size_t)(c0 + c * 16 + r16) * KPAD + kb * 32 + g4 * 8);
    __builtin_amdgcn_sched_barrier(0);
    dma_tile(y + (t0 + 0) * TFLOAT, yf + 0 * BUFSTRIDE, wid, lane);
    __builtin_amdgcn_sched_barrier(0);
    dma_tile(y + (t0 + 1) * TFLOAT, yf + 1 * BUFSTRIDE, wid, lane);
    __builtin_amdgcn_sched_barrier(0);

    // ---- iter 0: wait D0 (bw drain too); D2 in flight after issue ----
    asm volatile("s_waitcnt vmcnt(3) lgkmcnt(0)" ::: "memory");
    SBAR();
    dma_tile(y + (t0 + 2) * TFLOAT, yf + 2 * BUFSTRIDE, wid, lane);
    __builtin_amdgcn_sched_barrier(0);
    compute_tile32(yf + 0 * BUFSTRIDE, bw, out, (t0 + 0) * TROWS, r16, g4, c0);

    // ---- iter 1: queue [D1,D2,st0] -> wait D1 = vmcnt(11) ----
    asm volatile("s_waitcnt vmcnt(11)" ::: "memory");
    SBAR();                                     // all waves done compute(0)
    dma_tile(y + (t0 + 3) * TFLOAT, yf + 0 * BUFSTRIDE, wid, lane);
    __builtin_amdgcn_sched_barrier(0);
    compute_tile32(yf + 1 * BUFSTRIDE, bw, out, (t0 + 1) * TROWS, r16, g4, c0);

    // ---- iter 2: queue [D2,st0,D3,st1] -> wait D2 = vmcnt(19) ----
    asm volatile("s_waitcnt vmcnt(19)" ::: "memory");
    SBAR();
    compute_tile32(yf + 2 * BUFSTRIDE, bw, out, (t0 + 2) * TROWS, r16, g4, c0);

    // ---- iter 3: queue [D3,st1,st2] -> wait D3 = vmcnt(16) ----
    asm volatile("s_waitcnt vmcnt(16)" ::: "memory");
    SBAR();
    compute_tile32(yf + 0 * BUFSTRIDE, bw, out, (t0 + 3) * TROWS, r16, g4, c0);
}

extern "C" void kernel_launch(void* const* d_in, const int* in_sizes, int n_in,
                              void* d_out, int out_size, void* d_ws, size_t ws_size,
                              hipStream_t stream) {
    const float* y     = (const float*)d_in[0];
    const float* omega = (const float*)d_in[1];
    const float* stdv  = (const float*)d_in[2];
    const float* mask  = (const float*)d_in[3];
    float* out = (float*)d_out;

    unsigned short* wT = (unsigned short*)d_ws;           // 256*96 bf16

    int R = in_sizes[0] / NNOTES;                         // 131072 rows
    int blocks = R / (4 * TROWS);                         // 1024

    harm_prep<<<KPAD, 256, 0, stream>>>(omega, stdv, mask, wT);
    harm_gemm<<<blocks, 256, 0, stream>>>(y, wT, out);
}